// Round 20
// baseline (145.425 us; speedup 1.0000x reference)
//
#include <hip/hip_runtime.h>

typedef __attribute__((ext_vector_type(8))) short bf16x8;
typedef __attribute__((ext_vector_type(4))) short short4v;
typedef __attribute__((ext_vector_type(4))) float f32x4;

// B=128, N=256, D=256, H=4 ; per-batch matrices are [256][256] (65536 elems)

__device__ __forceinline__ float b2f(short s){
  unsigned u = ((unsigned)(unsigned short)s) << 16;
  return __builtin_bit_cast(float, u);
}
__device__ __forceinline__ short f2b(float f){
  unsigned u = __builtin_bit_cast(unsigned, f);
  u = (u + 0x7FFFu + ((u >> 16) & 1u)) >> 16;
  return (short)(unsigned short)u;
}

// XOR swizzle for 512B-stride rows: spread across the 8 16B-slot orbit.
#define SWZ(row, bytecol) ((((row) * 512) + (bytecol)) ^ (((row) & 7) << 4))

// -------- transpose-convert f32 [256][256] -> bf16 ^T : z=0 fc_w->WT, z=1..4 kernels->KhT --------
__global__ __launch_bounds__(256) void ktrans(const float* __restrict__ fcw, const float* __restrict__ kers,
                                              short* __restrict__ WT, short* __restrict__ KhT){
  __shared__ float tile[32][33];
  int z = blockIdx.z;
  const float* src = (z == 0) ? fcw : (kers + (z-1)*65536);
  short* dst = (z == 0) ? WT : (KhT + (z-1)*65536);
  int x0 = blockIdx.x*32, y0 = blockIdx.y*32;
  int tx = threadIdx.x & 31, ty = threadIdx.x >> 5;
  #pragma unroll
  for (int i = 0; i < 32; i += 8) tile[ty+i][tx] = src[(y0+ty+i)*256 + x0+tx];
  __syncthreads();
  #pragma unroll
  for (int i = 0; i < 32; i += 8) dst[(x0+ty+i)*256 + y0+tx] = f2b(tile[tx][ty+i]);
}

// ======== kG12: per (b, f-half) — GEMM1 = W-half(A) @ atom(B, f32 inline-cvt):
//          f in reg-dim -> VECTOR G2nf global stores + scalar LDS G2T stores.
//          GEMM2 = G2T-LDS @ x(f32,cvt, xbits/diag on the fly) -> G1.
//          grid 256, 64KB LDS -> __launch_bounds__(512,2) gives 2 blocks/CU. ========
__global__ __launch_bounds__(512, 2) void kG12(const short* __restrict__ WT, const float* __restrict__ atom,
                                               const float* __restrict__ x,
                                               short* __restrict__ G2nf, short* __restrict__ G1,
                                               unsigned* __restrict__ xbits, float* __restrict__ diag){
  __shared__ __align__(16) char G2s[65536];   // [128 f-local][256 m] bf16, SWZ
  int wg = blockIdx.x;                 // 0..255
  int xcd = wg & 7, idx = wg >> 3;     // idx 0..31
  int b  = xcd + ((idx >> 1) << 3);    // 16 batches per xcd
  int fh = idx & 1;
  int tid = threadIdx.x, lane = tid & 63, w = tid >> 6;
  int lr = lane & 15, lq = lane >> 4, koff = lq * 8;

  // ---- GEMM1: D[f 128][m 256]; waves 4m x 2f ; A = WT rows f (reg-dim), B = atom rows m (lane) ----
  {
    int wm = (w >> 1) * 64, wf = (w & 1) * 64;
    const float* Ab = atom + b*65536;
    const short* Bw = WT + (fh*128 + wf)*256;
    f32x4 acc[4][4] = {};   // acc[jf][im]
    for (int k0 = 0; k0 < 256; k0 += 32){
      bf16x8 aw[4], bm[4];
      #pragma unroll
      for (int j = 0; j < 4; j++) aw[j] = *(const bf16x8*)(Bw + (j*16 + lr)*256 + k0 + koff);
      #pragma unroll
      for (int i = 0; i < 4; i++){
        const float* p = Ab + (wm + i*16 + lr)*256 + k0 + koff;
        f32x4 a0 = *(const f32x4*)p, a1 = *(const f32x4*)(p + 4);
        #pragma unroll
        for (int e = 0; e < 4; e++){ bm[i][e] = f2b(a0[e]); bm[i][4+e] = f2b(a1[e]); }
      }
      #pragma unroll
      for (int j = 0; j < 4; j++)
        #pragma unroll
        for (int i = 0; i < 4; i++)
          acc[j][i] = __builtin_amdgcn_mfma_f32_16x16x32_bf16(aw[j], bm[i], acc[j][i], 0, 0, 0);
    }
    // f = fh*128 + wf + j*16 + lq*4 + r (reg-dim), m = wm + i*16 + lr (lane-dim)
    #pragma unroll
    for (int j = 0; j < 4; j++)
      #pragma unroll
      for (int i = 0; i < 4; i++){
        short4v v;
        #pragma unroll
        for (int r = 0; r < 4; r++) v[r] = f2b(acc[j][i][r]);
        int m = wm + i*16 + lr;
        int flb = wf + j*16 + lq*4;                                    // local f base
        *(short4v*)(G2nf + b*65536 + m*256 + fh*128 + flb) = v;        // VECTOR global [m][f]
        #pragma unroll
        for (int r = 0; r < 4; r++)
          *(short*)(G2s + SWZ(flb + r, m*2)) = v[r];                   // scalar LDS G2T[f][m]
      }
  }
  __syncthreads();

  // ---- GEMM2: D[f-local][n] = G2T-LDS @ x ; waves 2f x 4n ; B converted inline + xbits/diag ----
  {
    int wf2 = (w >> 2) * 64, wn2 = (w & 3) * 64;
    const float* Xb = x + b*65536;
    f32x4 acc[4][4] = {};
    for (int k0 = 0; k0 < 256; k0 += 32){
      bf16x8 af[4], bfr[4];
      #pragma unroll
      for (int i = 0; i < 4; i++) af[i]  = *(const bf16x8*)(G2s + SWZ(wf2 + i*16 + lr, (k0 + koff)*2));
      #pragma unroll
      for (int j = 0; j < 4; j++){
        int n = wn2 + j*16 + lr;
        const float* p = Xb + n*256 + k0 + koff;
        f32x4 x0 = *(const f32x4*)p, x1 = *(const f32x4*)(p + 4);
        unsigned b8 = 0u;
        #pragma unroll
        for (int e = 0; e < 4; e++){
          bfr[j][e] = f2b(x0[e]);     if (x0[e] > 0.5f) b8 |= (1u << e);
          bfr[j][4+e] = f2b(x1[e]);   if (x1[e] > 0.5f) b8 |= (1u << (4 + e));
        }
        if (w < 4){   // waves 0-3 cover each n exactly once
          unsigned full = b8 << (lq * 8);
          full |= __shfl_xor(full, 16);
          full |= __shfl_xor(full, 32);
          if (lq == 0) xbits[(b*256 + n)*8 + (k0 >> 5)] = full;
          int nm = n & 31;
          if ((n & ~31) == k0 && (nm >> 3) == lq)
            diag[b*256 + n] = (nm & 4) ? x1[nm & 3] : x0[nm & 3];
        }
      }
      #pragma unroll
      for (int i = 0; i < 4; i++)
        #pragma unroll
        for (int j = 0; j < 4; j++)
          acc[i][j] = __builtin_amdgcn_mfma_f32_16x16x32_bf16(af[i], bfr[j], acc[i][j], 0, 0, 0);
    }
    // C^T: n = wn2 + j*16 + lr (lane), f = fh*128 + wf2 + i*16 + lq*4 + r (reg)
    #pragma unroll
    for (int i = 0; i < 4; i++)
      #pragma unroll
      for (int j = 0; j < 4; j++){
        short4v v;
        #pragma unroll
        for (int r = 0; r < 4; r++) v[r] = f2b(acc[i][j][r]);
        *(short4v*)(G1 + b*65536 + (wn2 + j*16 + lr)*256 + fh*128 + wf2 + i*16 + lq*4) = v;
      }
  }
}

// ======== kHead (R17/R19 verbatim): K in LDS, shared-h1s phase 1, swapped epilogue -> featS;
//          phase 2: wave-private in-register softmax (P = MFMA B-fragments), ZERO barriers. ========
__global__ __launch_bounds__(512, 1) void kHead(const short* __restrict__ KhT, const short* __restrict__ G1,
                                                const short* __restrict__ G2nf, const float* __restrict__ diag,
                                                const float* __restrict__ fcb, const float* __restrict__ epsv,
                                                const float* __restrict__ biases, const float* __restrict__ atts,
                                                const float* __restrict__ attn, const float* __restrict__ attbv,
                                                const unsigned* __restrict__ xbits,
                                                float* __restrict__ out, float* __restrict__ out2){
  __shared__ __align__(16) char featS[131072];    // phase1: K[o][k] SWZ ; then feat^T[o][n] SWZ
  __shared__ __align__(16) char scratch[24576];   // h1s[256][40] | post-phase1: red@0/2048, xbitsL@4096
  __shared__ float asvL[256], anvL[256], fcbL[256];

  short (*h1s)[40] = (short(*)[40])scratch;
  float (*red_s)[64] = (float(*)[64])(scratch);
  float (*red_n)[64] = (float(*)[64])(scratch + 2048);
  unsigned* xbitsL = (unsigned*)(scratch + 4096);

  int wg = blockIdx.x;
  int xcd = wg & 7, idx = wg >> 3;
  int b = xcd + ((idx >> 2) << 3);   // 16 batches per xcd, 4 heads adjacent
  int h = idx & 3;
  int tid = threadIdx.x, lane = tid & 63, w = tid >> 6;
  float epsm1 = epsv[h] - 1.0f;
  const short* KA  = KhT + h*65536;
  const short* G1b = G1  + b*65536;
  const short* G2b = G2nf + b*65536;

  // ---- stage K (128 KB) into featS, SWZ[o][k]; stage fcb ----
  {
    int o = tid >> 1, half = (tid & 1) * 128;
    #pragma unroll
    for (int q = 0; q < 16; q++){
      int kk = half + q*8;
      bf16x8 v = *(const bf16x8*)(KA + o*256 + kk);
      *(bf16x8*)(featS + SWZ(o, kk*2)) = v;
    }
    if (tid < 256) fcbL[tid] = fcb[tid];
  }

  // rebuild assignment: thread -> (row nl 0..255, 16-k half)
  int nl = tid >> 1, rkk = (tid & 1) * 16;
  float cj = epsm1 * diag[b*256 + nl];

  // wave geometry (phase 1)
  int wro = (w >> 2) * 128;   // o-half
  int wn  = (w & 3) * 64;     // n-quarter
  int lr = lane & 15, lq = lane >> 4;
  int koff = lq * 8;

  // prefetch G1/G2 for k-step 0
  bf16x8 p1a = *(const bf16x8*)(G1b + nl*256 + rkk);
  bf16x8 p1b = *(const bf16x8*)(G1b + nl*256 + rkk + 8);
  bf16x8 p2a = *(const bf16x8*)(G2b + nl*256 + rkk);
  bf16x8 p2b = *(const bf16x8*)(G2b + nl*256 + rkk + 8);

  __syncthreads();   // K + fcb staged

  // ---------------- phase 1: feat = h1 @ K_h (shared h1s rebuild, acc[j_n][i_o]) ----------------
  f32x4 acc[4][8] = {};
  for (int t = 0; t < 8; t++){
    int k0 = t*32;
    {
      bf16x8 o1, o2;
      #pragma unroll
      for (int e = 0; e < 8; e++){
        float v = b2f(p1a[e]) + cj*b2f(p2a[e]) + fcbL[k0 + rkk + e];
        v = v > 0.f ? v : 0.01f*v;
        o1[e] = f2b(v);
      }
      #pragma unroll
      for (int e = 0; e < 8; e++){
        float v = b2f(p1b[e]) + cj*b2f(p2b[e]) + fcbL[k0 + rkk + 8 + e];
        v = v > 0.f ? v : 0.01f*v;
        o2[e] = f2b(v);
      }
      *(bf16x8*)&h1s[nl][rkk] = o1;
      *(bf16x8*)&h1s[nl][rkk + 8] = o2;
    }
    __syncthreads();
    if (t < 7){
      int kn = k0 + 32;
      p1a = *(const bf16x8*)(G1b + nl*256 + kn + rkk);
      p1b = *(const bf16x8*)(G1b + nl*256 + kn + rkk + 8);
      p2a = *(const bf16x8*)(G2b + nl*256 + kn + rkk);
      p2b = *(const bf16x8*)(G2b + nl*256 + kn + rkk + 8);
    }
    bf16x8 af[4];
    #pragma unroll
    for (int j = 0; j < 4; j++) af[j] = *(const bf16x8*)&h1s[wn + j*16 + lr][koff];
    #pragma unroll
    for (int i = 0; i < 8; i++){
      bf16x8 bfv = *(const bf16x8*)(featS + SWZ(wro + i*16 + lr, (k0 + koff)*2));
      #pragma unroll
      for (int j = 0; j < 4; j++)
        acc[j][i] = __builtin_amdgcn_mfma_f32_16x16x32_bf16(af[j], bfv, acc[j][i], 0, 0, 0);
    }
    __syncthreads();
  }

  // ---------------- epilogue: bias + vectorized feat^T stores + a_s/a_n partials ----------------
  float ps[4][4] = {}, pn[4][4] = {};
  #pragma unroll
  for (int i = 0; i < 8; i++){
    int od = wro + i*16 + lr;                       // o (lane-dim)
    float bi  = biases[h*256 + od];
    float wsv = atts[h*256 + od];
    float wnv = attn[h*256 + od];
    #pragma unroll
    for (int j = 0; j < 4; j++){
      short4v sv;
      #pragma unroll
      for (int r = 0; r < 4; r++){
        float fv = acc[j][i][r] + bi;
        sv[r] = f2b(fv);
        ps[j][r] += fv * wsv;
        pn[j][r] += fv * wnv;
      }
      *(short4v*)(featS + SWZ(od, (wn + j*16 + lq*4)*2) ) = sv;   // 8B store
    }
  }
  #pragma unroll
  for (int j = 0; j < 4; j++)
    #pragma unroll
    for (int r = 0; r < 4; r++){
      float s = ps[j][r], nv = pn[j][r];
      s += __shfl_xor(s, 1); s += __shfl_xor(s, 2); s += __shfl_xor(s, 4); s += __shfl_xor(s, 8);
      nv += __shfl_xor(nv, 1); nv += __shfl_xor(nv, 2); nv += __shfl_xor(nv, 4); nv += __shfl_xor(nv, 8);
      ps[j][r] = s; pn[j][r] = nv;
    }
  // h1s dead (last read before final phase-1 barrier) -> red + xbitsL overlays safe
  if (lr == 0){
    #pragma unroll
    for (int j = 0; j < 4; j++)
      #pragma unroll
      for (int r = 0; r < 4; r++){
        red_s[w][j*16 + lq*4 + r] = ps[j][r];
        red_n[w][j*16 + lq*4 + r] = pn[j][r];
      }
  }
  {
    const unsigned* xb = xbits + b*2048;
    #pragma unroll
    for (int q = 0; q < 4; q++) xbitsL[tid*4 + q] = xb[tid*4 + q];
  }
  __syncthreads();
  if (tid < 256){
    int q = tid >> 6, nn = tid & 63;
    asvL[tid] = red_s[q][nn] + red_s[q+4][nn] + attbv[h];
    anvL[tid] = red_n[q][nn] + red_n[q+4][nn];
  }
  __syncthreads();

  // ---------------- phase 2: wave-private softmax + PV, ZERO barriers ----------------
  // Wave w owns i-rows [w*32, w*32+32). Lane (lr,lq) holds P[row][kv = t*32+lq*8 .. +8]
  // for t=0..7 — exactly the MFMA B-fragment layout for all 8 k-steps.
  int wi = w * 32;
  bf16x8 bfp[2][8];
  #pragma unroll
  for (int sub = 0; sub < 2; sub++){
    int i = wi + sub*16 + lr;
    float as_i = asvL[i];
    float Lv[8][8];
    float mx = -3.0e38f;
    #pragma unroll
    for (int t = 0; t < 8; t++){
      unsigned bits = xbitsL[i*8 + t] >> (lq*8);
      #pragma unroll
      for (int e = 0; e < 8; e++){
        float s = as_i + anvL[t*32 + lq*8 + e];
        float el = s > 0.f ? s : (__expf(s) - 1.0f);
        float L = el + (((bits >> e) & 1u) ? 0.f : -1.0e10f);
        Lv[t][e] = L; mx = fmaxf(mx, L);
      }
    }
    mx = fmaxf(mx, __shfl_xor(mx, 16));
    mx = fmaxf(mx, __shfl_xor(mx, 32));
    float sum = 0.f;
    #pragma unroll
    for (int t = 0; t < 8; t++)
      #pragma unroll
      for (int e = 0; e < 8; e++){ float p = __expf(Lv[t][e] - mx); Lv[t][e] = p; sum += p; }
    sum += __shfl_xor(sum, 16);
    sum += __shfl_xor(sum, 32);
    float inv = 1.0f / sum;
    #pragma unroll
    for (int t = 0; t < 8; t++){
      bf16x8 pv;
      #pragma unroll
      for (int e = 0; e < 8; e++) pv[e] = f2b(Lv[t][e] * inv);
      bfp[sub][t] = pv;
    }
    if (h == 3){
      float* o2 = out2 + b*65536 + i*256 + lq*8;
      #pragma unroll
      for (int t = 0; t < 8; t++){
        f32x4 v0, v1;
        #pragma unroll
        for (int e = 0; e < 4; e++){ v0[e] = Lv[t][e]*inv; v1[e] = Lv[t][4+e]*inv; }
        *(f32x4*)(o2 + t*32) = v0;
        *(f32x4*)(o2 + t*32 + 4) = v1;
      }
    }
  }

  // PV: 16 o-tiles; afv reused for both i-subtiles; no barriers, waves drift freely.
  float* outb = out + (size_t)(b*256 + wi)*1024 + h*256;
  #pragma unroll 1
  for (int ot = 0; ot < 16; ot++){
    f32x4 a2[2] = {};
    #pragma unroll
    for (int t = 0; t < 8; t++){
      bf16x8 afv = *(const bf16x8*)(featS + SWZ(ot*16 + lr, (t*32 + lq*8)*2));
      a2[0] = __builtin_amdgcn_mfma_f32_16x16x32_bf16(afv, bfp[0][t], a2[0], 0, 0, 0);
      a2[1] = __builtin_amdgcn_mfma_f32_16x16x32_bf16(afv, bfp[1][t], a2[1], 0, 0, 0);
    }
    *(f32x4*)(outb + (size_t)(lr)*1024 + ot*16 + lq*4) = a2[0];
    *(f32x4*)(outb + (size_t)(16 + lr)*1024 + ot*16 + lq*4) = a2[1];
  }
}

extern "C" void kernel_launch(void* const* d_in, const int* in_sizes, int n_in,
                              void* d_out, int out_size, void* d_ws, size_t ws_size,
                              hipStream_t stream) {
  const float* atom   = (const float*)d_in[0];
  const float* x      = (const float*)d_in[1];
  const float* fc_w   = (const float*)d_in[2];
  const float* fc_b   = (const float*)d_in[3];
  const float* kers   = (const float*)d_in[4];
  const float* att_s  = (const float*)d_in[5];
  const float* att_n  = (const float*)d_in[6];
  const float* eps    = (const float*)d_in[7];
  const float* biases = (const float*)d_in[8];
  const float* att_b  = (const float*)d_in[9];

  // ws layout (~34 MB)
  char* w = (char*)d_ws;
  short* WT      = (short*)(w);                      // [0,        131072)
  short* KhT     = (short*)(w + 131072);             // [131072,   655360)
  float* diag    = (float*)(w + 655360);             // [655360,   786432)
  unsigned* xbits= (unsigned*)(w + 786432);          // [786432,  1835008)
  short* G2nf    = (short*)(w + 1835008);            // [1835008, 18612224)
  short* G1      = (short*)(w + 18612224);           // [18612224, 35389440)

  float* out  = (float*)d_out;
  float* out2 = out + 33554432;  // B*N*H*D floats

  ktrans<<<dim3(8, 8, 5), 256, 0, stream>>>(fc_w, kers, WT, KhT);
  kG12<<<dim3(256), 512, 0, stream>>>(WT, atom, x, G2nf, G1, xbits, diag);
  kHead<<<dim3(512), 512, 0, stream>>>(KhT, G1, G2nf, diag, fc_b, eps,
                                       biases, att_s, att_n, att_b, xbits, out, out2);
}

// Round 21
// 143.916 us; speedup vs baseline: 1.0105x; 1.0105x over previous
//
#include <hip/hip_runtime.h>

typedef __attribute__((ext_vector_type(8))) short bf16x8;
typedef __attribute__((ext_vector_type(4))) short short4v;
typedef __attribute__((ext_vector_type(4))) float f32x4;

// B=128, N=256, D=256, H=4 ; per-batch matrices are [256][256] (65536 elems)

__device__ __forceinline__ float b2f(short s){
  unsigned u = ((unsigned)(unsigned short)s) << 16;
  return __builtin_bit_cast(float, u);
}
__device__ __forceinline__ short f2b(float f){
  unsigned u = __builtin_bit_cast(unsigned, f);
  u = (u + 0x7FFFu + ((u >> 16) & 1u)) >> 16;
  return (short)(unsigned short)u;
}

// XOR swizzle for 512B-stride rows: spread across the 8 16B-slot orbit.
#define SWZ(row, bytecol) ((((row) * 512) + (bytecol)) ^ (((row) & 7) << 4))

// -------- transpose-convert f32 [256][256] -> bf16 ^T : z=0 fc_w->WT, z=1..4 kernels->KhT --------
__global__ __launch_bounds__(256) void ktrans(const float* __restrict__ fcw, const float* __restrict__ kers,
                                              short* __restrict__ WT, short* __restrict__ KhT){
  __shared__ float tile[32][33];
  int z = blockIdx.z;
  const float* src = (z == 0) ? fcw : (kers + (z-1)*65536);
  short* dst = (z == 0) ? WT : (KhT + (z-1)*65536);
  int x0 = blockIdx.x*32, y0 = blockIdx.y*32;
  int tx = threadIdx.x & 31, ty = threadIdx.x >> 5;
  #pragma unroll
  for (int i = 0; i < 32; i += 8) tile[ty+i][tx] = src[(y0+ty+i)*256 + x0+tx];
  __syncthreads();
  #pragma unroll
  for (int i = 0; i < 32; i += 8) dst[(x0+ty+i)*256 + y0+tx] = f2b(tile[tx][ty+i]);
}

// ======== kG12: per (b, f-half) — GEMM1 = W-half(A) @ atom(B, f32 inline-cvt):
//          f in reg-dim -> VECTOR G2nf global stores + scalar LDS G2T stores.
//          GEMM2 = G2T-LDS @ x(f32,cvt, xbits/diag on the fly) -> G1. grid 256. ========
__global__ __launch_bounds__(512, 1) void kG12(const short* __restrict__ WT, const float* __restrict__ atom,
                                               const float* __restrict__ x,
                                               short* __restrict__ G2nf, short* __restrict__ G1,
                                               unsigned* __restrict__ xbits, float* __restrict__ diag){
  __shared__ __align__(16) char G2s[65536];   // [128 f-local][256 m] bf16, SWZ
  int wg = blockIdx.x;                 // 0..255
  int xcd = wg & 7, idx = wg >> 3;     // idx 0..31
  int b  = xcd + ((idx >> 1) << 3);    // 16 batches per xcd
  int fh = idx & 1;
  int tid = threadIdx.x, lane = tid & 63, w = tid >> 6;
  int lr = lane & 15, lq = lane >> 4, koff = lq * 8;

  // ---- GEMM1: D[f 128][m 256]; waves 4m x 2f ; A = WT rows f (reg-dim), B = atom rows m (lane) ----
  {
    int wm = (w >> 1) * 64, wf = (w & 1) * 64;
    const float* Ab = atom + b*65536;
    const short* Bw = WT + (fh*128 + wf)*256;
    f32x4 acc[4][4] = {};   // acc[jf][im]
    for (int k0 = 0; k0 < 256; k0 += 32){
      bf16x8 aw[4], bm[4];
      #pragma unroll
      for (int j = 0; j < 4; j++) aw[j] = *(const bf16x8*)(Bw + (j*16 + lr)*256 + k0 + koff);
      #pragma unroll
      for (int i = 0; i < 4; i++){
        const float* p = Ab + (wm + i*16 + lr)*256 + k0 + koff;
        f32x4 a0 = *(const f32x4*)p, a1 = *(const f32x4*)(p + 4);
        #pragma unroll
        for (int e = 0; e < 4; e++){ bm[i][e] = f2b(a0[e]); bm[i][4+e] = f2b(a1[e]); }
      }
      #pragma unroll
      for (int j = 0; j < 4; j++)
        #pragma unroll
        for (int i = 0; i < 4; i++)
          acc[j][i] = __builtin_amdgcn_mfma_f32_16x16x32_bf16(aw[j], bm[i], acc[j][i], 0, 0, 0);
    }
    // f = fh*128 + wf + j*16 + lq*4 + r (reg-dim), m = wm + i*16 + lr (lane-dim)
    #pragma unroll
    for (int j = 0; j < 4; j++)
      #pragma unroll
      for (int i = 0; i < 4; i++){
        short4v v;
        #pragma unroll
        for (int r = 0; r < 4; r++) v[r] = f2b(acc[j][i][r]);
        int m = wm + i*16 + lr;
        int flb = wf + j*16 + lq*4;                                    // local f base
        *(short4v*)(G2nf + b*65536 + m*256 + fh*128 + flb) = v;        // VECTOR global [m][f]
        #pragma unroll
        for (int r = 0; r < 4; r++)
          *(short*)(G2s + SWZ(flb + r, m*2)) = v[r];                   // scalar LDS G2T[f][m]
      }
  }
  __syncthreads();

  // ---- GEMM2: D[f-local][n] = G2T-LDS @ x ; waves 2f x 4n ; B converted inline + xbits/diag ----
  {
    int wf2 = (w >> 2) * 64, wn2 = (w & 3) * 64;
    const float* Xb = x + b*65536;
    f32x4 acc[4][4] = {};
    for (int k0 = 0; k0 < 256; k0 += 32){
      bf16x8 af[4], bfr[4];
      #pragma unroll
      for (int i = 0; i < 4; i++) af[i]  = *(const bf16x8*)(G2s + SWZ(wf2 + i*16 + lr, (k0 + koff)*2));
      #pragma unroll
      for (int j = 0; j < 4; j++){
        int n = wn2 + j*16 + lr;
        const float* p = Xb + n*256 + k0 + koff;
        f32x4 x0 = *(const f32x4*)p, x1 = *(const f32x4*)(p + 4);
        unsigned b8 = 0u;
        #pragma unroll
        for (int e = 0; e < 4; e++){
          bfr[j][e] = f2b(x0[e]);     if (x0[e] > 0.5f) b8 |= (1u << e);
          bfr[j][4+e] = f2b(x1[e]);   if (x1[e] > 0.5f) b8 |= (1u << (4 + e));
        }
        if (w < 4){   // waves 0-3 cover each n exactly once
          unsigned full = b8 << (lq * 8);
          full |= __shfl_xor(full, 16);
          full |= __shfl_xor(full, 32);
          if (lq == 0) xbits[(b*256 + n)*8 + (k0 >> 5)] = full;
          int nm = n & 31;
          if ((n & ~31) == k0 && (nm >> 3) == lq)
            diag[b*256 + n] = (nm & 4) ? x1[nm & 3] : x0[nm & 3];
        }
      }
      #pragma unroll
      for (int i = 0; i < 4; i++)
        #pragma unroll
        for (int j = 0; j < 4; j++)
          acc[i][j] = __builtin_amdgcn_mfma_f32_16x16x32_bf16(af[i], bfr[j], acc[i][j], 0, 0, 0);
    }
    // C^T: n = wn2 + j*16 + lr (lane), f = fh*128 + wf2 + i*16 + lq*4 + r (reg)
    #pragma unroll
    for (int i = 0; i < 4; i++)
      #pragma unroll
      for (int j = 0; j < 4; j++){
        short4v v;
        #pragma unroll
        for (int r = 0; r < 4; r++) v[r] = f2b(acc[i][j][r]);
        *(short4v*)(G1 + b*65536 + (wn2 + j*16 + lr)*256 + fh*128 + wf2 + i*16 + lq*4) = v;
      }
  }
}

// ======== kHead: K in LDS, shared-h1s phase 1, swapped epilogue -> featS;
//          phase 2: wave-private in-register softmax, ZERO barriers, setprio'd PV. ========
__global__ __launch_bounds__(512, 1) void kHead(const short* __restrict__ KhT, const short* __restrict__ G1,
                                                const short* __restrict__ G2nf, const float* __restrict__ diag,
                                                const float* __restrict__ fcb, const float* __restrict__ epsv,
                                                const float* __restrict__ biases, const float* __restrict__ atts,
                                                const float* __restrict__ attn, const float* __restrict__ attbv,
                                                const unsigned* __restrict__ xbits,
                                                float* __restrict__ out, float* __restrict__ out2){
  __shared__ __align__(16) char featS[131072];    // phase1: K[o][k] SWZ ; then feat^T[o][n] SWZ
  __shared__ __align__(16) char scratch[24576];   // h1s[256][40] | post-phase1: red@0/2048, xbitsL@4096
  __shared__ float asvL[256], anvL[256], fcbL[256];

  short (*h1s)[40] = (short(*)[40])scratch;
  float (*red_s)[64] = (float(*)[64])(scratch);
  float (*red_n)[64] = (float(*)[64])(scratch + 2048);
  unsigned* xbitsL = (unsigned*)(scratch + 4096);

  int wg = blockIdx.x;
  int xcd = wg & 7, idx = wg >> 3;
  int b = xcd + ((idx >> 2) << 3);   // 16 batches per xcd, 4 heads adjacent
  int h = idx & 3;
  int tid = threadIdx.x, lane = tid & 63, w = tid >> 6;
  float epsm1 = epsv[h] - 1.0f;
  const short* KA  = KhT + h*65536;
  const short* G1b = G1  + b*65536;
  const short* G2b = G2nf + b*65536;

  // ---- stage K (128 KB) into featS, SWZ[o][k]; stage fcb ----
  {
    int o = tid >> 1, half = (tid & 1) * 128;
    #pragma unroll
    for (int q = 0; q < 16; q++){
      int kk = half + q*8;
      bf16x8 v = *(const bf16x8*)(KA + o*256 + kk);
      *(bf16x8*)(featS + SWZ(o, kk*2)) = v;
    }
    if (tid < 256) fcbL[tid] = fcb[tid];
  }

  // rebuild assignment: thread -> (row nl 0..255, 16-k half)
  int nl = tid >> 1, rkk = (tid & 1) * 16;
  float cj = epsm1 * diag[b*256 + nl];

  // wave geometry (phase 1)
  int wro = (w >> 2) * 128;   // o-half
  int wn  = (w & 3) * 64;     // n-quarter
  int lr = lane & 15, lq = lane >> 4;
  int koff = lq * 8;

  // prefetch G1/G2 for k-step 0
  bf16x8 p1a = *(const bf16x8*)(G1b + nl*256 + rkk);
  bf16x8 p1b = *(const bf16x8*)(G1b + nl*256 + rkk + 8);
  bf16x8 p2a = *(const bf16x8*)(G2b + nl*256 + rkk);
  bf16x8 p2b = *(const bf16x8*)(G2b + nl*256 + rkk + 8);

  __syncthreads();   // K + fcb staged

  // ---------------- phase 1: feat = h1 @ K_h (shared h1s rebuild, acc[j_n][i_o]) ----------------
  f32x4 acc[4][8] = {};
  for (int t = 0; t < 8; t++){
    int k0 = t*32;
    {
      bf16x8 o1, o2;
      #pragma unroll
      for (int e = 0; e < 8; e++){
        float v = b2f(p1a[e]) + cj*b2f(p2a[e]) + fcbL[k0 + rkk + e];
        o1[e] = f2b(fmaxf(v, 0.01f*v));
      }
      #pragma unroll
      for (int e = 0; e < 8; e++){
        float v = b2f(p1b[e]) + cj*b2f(p2b[e]) + fcbL[k0 + rkk + 8 + e];
        o2[e] = f2b(fmaxf(v, 0.01f*v));
      }
      *(bf16x8*)&h1s[nl][rkk] = o1;
      *(bf16x8*)&h1s[nl][rkk + 8] = o2;
    }
    __syncthreads();
    if (t < 7){
      int kn = k0 + 32;
      p1a = *(const bf16x8*)(G1b + nl*256 + kn + rkk);
      p1b = *(const bf16x8*)(G1b + nl*256 + kn + rkk + 8);
      p2a = *(const bf16x8*)(G2b + nl*256 + kn + rkk);
      p2b = *(const bf16x8*)(G2b + nl*256 + kn + rkk + 8);
    }
    bf16x8 af[4];
    #pragma unroll
    for (int j = 0; j < 4; j++) af[j] = *(const bf16x8*)&h1s[wn + j*16 + lr][koff];
    #pragma unroll
    for (int i = 0; i < 8; i++){
      bf16x8 bfv = *(const bf16x8*)(featS + SWZ(wro + i*16 + lr, (k0 + koff)*2));
      #pragma unroll
      for (int j = 0; j < 4; j++)
        acc[j][i] = __builtin_amdgcn_mfma_f32_16x16x32_bf16(af[j], bfv, acc[j][i], 0, 0, 0);
    }
    __syncthreads();
  }

  // ---------------- epilogue: bias + vectorized feat^T stores + a_s/a_n partials ----------------
  float ps[4][4] = {}, pn[4][4] = {};
  #pragma unroll
  for (int i = 0; i < 8; i++){
    int od = wro + i*16 + lr;                       // o (lane-dim)
    float bi  = biases[h*256 + od];
    float wsv = atts[h*256 + od];
    float wnv = attn[h*256 + od];
    #pragma unroll
    for (int j = 0; j < 4; j++){
      short4v sv;
      #pragma unroll
      for (int r = 0; r < 4; r++){
        float fv = acc[j][i][r] + bi;
        sv[r] = f2b(fv);
        ps[j][r] += fv * wsv;
        pn[j][r] += fv * wnv;
      }
      *(short4v*)(featS + SWZ(od, (wn + j*16 + lq*4)*2) ) = sv;   // 8B store
    }
  }
  #pragma unroll
  for (int j = 0; j < 4; j++)
    #pragma unroll
    for (int r = 0; r < 4; r++){
      float s = ps[j][r], nv = pn[j][r];
      s += __shfl_xor(s, 1); s += __shfl_xor(s, 2); s += __shfl_xor(s, 4); s += __shfl_xor(s, 8);
      nv += __shfl_xor(nv, 1); nv += __shfl_xor(nv, 2); nv += __shfl_xor(nv, 4); nv += __shfl_xor(nv, 8);
      ps[j][r] = s; pn[j][r] = nv;
    }
  // h1s dead (last read before final phase-1 barrier) -> red + xbitsL overlays safe
  if (lr == 0){
    #pragma unroll
    for (int j = 0; j < 4; j++)
      #pragma unroll
      for (int r = 0; r < 4; r++){
        red_s[w][j*16 + lq*4 + r] = ps[j][r];
        red_n[w][j*16 + lq*4 + r] = pn[j][r];
      }
  }
  {
    const unsigned* xb = xbits + b*2048;
    #pragma unroll
    for (int q = 0; q < 4; q++) xbitsL[tid*4 + q] = xb[tid*4 + q];
  }
  __syncthreads();
  if (tid < 256){
    int q = tid >> 6, nn = tid & 63;
    asvL[tid] = red_s[q][nn] + red_s[q+4][nn] + attbv[h];
    anvL[tid] = red_n[q][nn] + red_n[q+4][nn];
  }
  __syncthreads();

  // ---------------- phase 2: wave-private softmax + PV, ZERO barriers ----------------
  // Wave w owns i-rows [w*32, w*32+32). Lane (lr,lq) holds P[row][kv = t*32+lq*8 .. +8]
  // for t=0..7 — exactly the MFMA B-fragment layout for all 8 k-steps.
  int wi = w * 32;
  bf16x8 bfp[2][8];
  #pragma unroll
  for (int sub = 0; sub < 2; sub++){
    int i = wi + sub*16 + lr;
    float as_i = asvL[i];
    float Lv[8][8];
    float mx = -3.0e38f;
    #pragma unroll
    for (int t = 0; t < 8; t++){
      unsigned bits = xbitsL[i*8 + t] >> (lq*8);
      #pragma unroll
      for (int e = 0; e < 8; e++){
        float s = as_i + anvL[t*32 + lq*8 + e];
        float el = s > 0.f ? s : (__expf(s) - 1.0f);
        float L = el + (((bits >> e) & 1u) ? 0.f : -1.0e10f);
        Lv[t][e] = L; mx = fmaxf(mx, L);
      }
    }
    mx = fmaxf(mx, __shfl_xor(mx, 16));
    mx = fmaxf(mx, __shfl_xor(mx, 32));
    float sum = 0.f;
    #pragma unroll
    for (int t = 0; t < 8; t++)
      #pragma unroll
      for (int e = 0; e < 8; e++){ float p = __expf(Lv[t][e] - mx); Lv[t][e] = p; sum += p; }
    sum += __shfl_xor(sum, 16);
    sum += __shfl_xor(sum, 32);
    float inv = 1.0f / sum;
    #pragma unroll
    for (int t = 0; t < 8; t++){
      bf16x8 pv;
      #pragma unroll
      for (int e = 0; e < 8; e++) pv[e] = f2b(Lv[t][e] * inv);
      bfp[sub][t] = pv;
    }
    if (h == 3){
      float* o2 = out2 + b*65536 + i*256 + lq*8;
      #pragma unroll
      for (int t = 0; t < 8; t++){
        f32x4 v0, v1;
        #pragma unroll
        for (int e = 0; e < 4; e++){ v0[e] = Lv[t][e]*inv; v1[e] = Lv[t][4+e]*inv; }
        *(f32x4*)(o2 + t*32) = v0;
        *(f32x4*)(o2 + t*32 + 4) = v1;
      }
    }
  }

  // PV: 16 o-tiles; afv reused for both i-subtiles; no barriers, waves drift freely.
  // setprio(1) around the MFMA cluster: waves here compete with softmax-VALU waves (T5 regime).
  float* outb = out + (size_t)(b*256 + wi)*1024 + h*256;
  #pragma unroll 1
  for (int ot = 0; ot < 16; ot++){
    f32x4 a2[2] = {};
    __builtin_amdgcn_s_setprio(1);
    #pragma unroll
    for (int t = 0; t < 8; t++){
      bf16x8 afv = *(const bf16x8*)(featS + SWZ(ot*16 + lr, (t*32 + lq*8)*2));
      a2[0] = __builtin_amdgcn_mfma_f32_16x16x32_bf16(afv, bfp[0][t], a2[0], 0, 0, 0);
      a2[1] = __builtin_amdgcn_mfma_f32_16x16x32_bf16(afv, bfp[1][t], a2[1], 0, 0, 0);
    }
    __builtin_amdgcn_s_setprio(0);
    *(f32x4*)(outb + (size_t)(lr)*1024 + ot*16 + lq*4) = a2[0];
    *(f32x4*)(outb + (size_t)(16 + lr)*1024 + ot*16 + lq*4) = a2[1];
  }
}

extern "C" void kernel_launch(void* const* d_in, const int* in_sizes, int n_in,
                              void* d_out, int out_size, void* d_ws, size_t ws_size,
                              hipStream_t stream) {
  const float* atom   = (const float*)d_in[0];
  const float* x      = (const float*)d_in[1];
  const float* fc_w   = (const float*)d_in[2];
  const float* fc_b   = (const float*)d_in[3];
  const float* kers   = (const float*)d_in[4];
  const float* att_s  = (const float*)d_in[5];
  const float* att_n  = (const float*)d_in[6];
  const float* eps    = (const float*)d_in[7];
  const float* biases = (const float*)d_in[8];
  const float* att_b  = (const float*)d_in[9];

  // ws layout (~34 MB)
  char* w = (char*)d_ws;
  short* WT      = (short*)(w);                      // [0,        131072)
  short* KhT     = (short*)(w + 131072);             // [131072,   655360)
  float* diag    = (float*)(w + 655360);             // [655360,   786432)
  unsigned* xbits= (unsigned*)(w + 786432);          // [786432,  1835008)
  short* G2nf    = (short*)(w + 1835008);            // [1835008, 18612224)
  short* G1      = (short*)(w + 18612224);           // [18612224, 35389440)

  float* out  = (float*)d_out;
  float* out2 = out + 33554432;  // B*N*H*D floats

  ktrans<<<dim3(8, 8, 5), 256, 0, stream>>>(fc_w, kers, WT, KhT);
  kG12<<<dim3(256), 512, 0, stream>>>(WT, atom, x, G2nf, G1, xbits, diag);
  kHead<<<dim3(512), 512, 0, stream>>>(KhT, G1, G2nf, diag, fc_b, eps,
                                       biases, att_s, att_n, att_b, xbits, out, out2);
}